// Round 2
// baseline (2852.438 us; speedup 1.0000x reference)
//
#include <hip/hip_runtime.h>
#include <hip/hip_bf16.h>

typedef short bf16x8 __attribute__((ext_vector_type(8)));
typedef float f32x4 __attribute__((ext_vector_type(4)));

constexpr int NN = 100000;           // nodes
constexpr int NE = 1600000;          // edges
constexpr int HH = 128;              // hidden
constexpr int NR = 8;                // relations
constexpr int NK = NR * NN;          // 800000 (rel,dst) segment keys
constexpr int SCAN_BLOCKS = (NK + 1023) / 1024;   // 782
constexpr int LDAA = 132;            // fp32 dwords per A_acc row (+4 pad)
constexpr int LDB  = 136;            // bf16 per B_lds row (+8 pad)

__device__ __forceinline__ unsigned short f2bf(float f) {
    unsigned b = __float_as_uint(f);
    b += 0x7fffu + ((b >> 16) & 1u);       // round-to-nearest-even
    return (unsigned short)(b >> 16);
}

__device__ __forceinline__ ushort2 cvt2bf(float a, float b) {
    union { __hip_bfloat162 h; ushort2 s; } u;
    u.h = __float22bfloat162_rn(float2{a, b});
    return u.s;
}

// ---- W convert + transpose: Wt[L][s][f][d] (bf16) from fp32 W[d][f] ----
__global__ void convertW(const float* __restrict__ Wr0, const float* __restrict__ Wq0,
                         const float* __restrict__ Wr1, const float* __restrict__ Wq1,
                         unsigned short* __restrict__ Wt) {
    int o = blockIdx.x * blockDim.x + threadIdx.x;
    if (o >= 2 * 9 * 128 * 128) return;
    int L = o / 147456;
    int rem = o - L * 147456;
    int s = rem >> 14;
    int p = rem & 16383;
    int f = p >> 7;
    int d = p & 127;
    const float* Wq = L ? Wq1 : Wq0;
    const float* Wr = L ? Wr1 : Wr0;
    float v = (s == 0) ? Wq[d * 128 + f] : Wr[((s - 1) * 128 + d) * 128 + f];
    Wt[o] = f2bf(v);
}

// ---- x -> bf16 split-halves format: xs[n][l] = pack(x[n][l], x[n][l+64]) ----
__global__ void convertX(const int* __restrict__ node_idx, const float* __restrict__ emb,
                         unsigned* __restrict__ xs) {
    int i = blockIdx.x * blockDim.x + threadIdx.x;
    if (i >= NN * 64) return;
    int n = i >> 6, l = i & 63;
    int row = node_idx[n];
    float a = emb[(size_t)row * HH + l];
    float b = emb[(size_t)row * HH + 64 + l];
    xs[(size_t)n * 64 + l] = (unsigned)f2bf(a) | ((unsigned)f2bf(b) << 16);
}

// ---- degree count per (rel,dst) key ----
__global__ void countDeg(const int* __restrict__ edst, const int* __restrict__ etype,
                         unsigned* __restrict__ counts) {
    int e = blockIdx.x * blockDim.x + threadIdx.x;
    if (e >= NE) return;
    int key = etype[e] * NN + edst[e];
    atomicAdd(&counts[key], 1u);
}

// ---- 2-level exclusive scan of counts[NK] -> starts ----
__global__ void scan1(const unsigned* __restrict__ counts, unsigned* __restrict__ starts,
                      unsigned* __restrict__ bsums) {
    __shared__ unsigned sh[256];
    int tid = threadIdx.x;
    int base = blockIdx.x * 1024 + tid * 4;
    unsigned c[4], tsum = 0;
#pragma unroll
    for (int j = 0; j < 4; ++j) {
        c[j] = (base + j < NK) ? counts[base + j] : 0u;
        tsum += c[j];
    }
    sh[tid] = tsum;
    __syncthreads();
    for (int ofs = 1; ofs < 256; ofs <<= 1) {
        unsigned v = (tid >= ofs) ? sh[tid - ofs] : 0u;
        __syncthreads();
        sh[tid] += v;
        __syncthreads();
    }
    unsigned run = sh[tid] - tsum;
#pragma unroll
    for (int j = 0; j < 4; ++j) {
        if (base + j < NK) starts[base + j] = run;
        run += c[j];
    }
    if (tid == 255) bsums[blockIdx.x] = sh[255];
}

__global__ void scan2(unsigned* __restrict__ bsums, int nb) {
    __shared__ unsigned sh[1024];
    int tid = threadIdx.x;
    unsigned v = (tid < nb) ? bsums[tid] : 0u;
    sh[tid] = v;
    __syncthreads();
    for (int ofs = 1; ofs < 1024; ofs <<= 1) {
        unsigned t = (tid >= ofs) ? sh[tid - ofs] : 0u;
        __syncthreads();
        sh[tid] += t;
        __syncthreads();
    }
    if (tid < nb) bsums[tid] = sh[tid] - v;
}

__global__ void scan3(unsigned* __restrict__ starts, unsigned* __restrict__ cursor,
                      const unsigned* __restrict__ bsums) {
    int i = blockIdx.x * blockDim.x + threadIdx.x;
    if (i >= NK) return;
    unsigned v = starts[i] + bsums[i >> 10];
    starts[i] = v;
    cursor[i] = v;
    if (i == 0) starts[NK] = NE;
}

// ---- counting-sort scatter: epk holds src | (dst&63)<<17 grouped by key ----
__global__ void scatterEdges(const int* __restrict__ esrc, const int* __restrict__ edst,
                             const int* __restrict__ etype, unsigned* __restrict__ cursor,
                             unsigned* __restrict__ epk) {
    int e = blockIdx.x * blockDim.x + threadIdx.x;
    if (e >= NE) return;
    int d = edst[e];
    int key = etype[e] * NN + d;
    unsigned pos = atomicAdd(&cursor[key], 1u);
    epk[pos] = (unsigned)esrc[e] | (((unsigned)d & 63u) << 17);
}

// ---- fused RGCN layer: per 64-node block, gather+mean in LDS, then MFMA ----
// xs: split-format bf16 input.  outS (layer0): split-format bf16.  outF (layer1): fp32.
__global__ __launch_bounds__(256, 2) void rgcnFused(
        const unsigned* __restrict__ xs, const unsigned* __restrict__ starts,
        const unsigned* __restrict__ epk, const unsigned short* __restrict__ Wt,
        const float* __restrict__ bias, float* __restrict__ outF,
        unsigned* __restrict__ outS) {
    __shared__ float A_acc[64 * LDAA];                   // 33.8 KB fp32 accum tile
    __shared__ __align__(16) unsigned short B_lds[128 * LDB];  // 34.8 KB weight segment
    __shared__ float invdeg[64];
    __shared__ unsigned erange[16];

    int tid = threadIdx.x;
    int wid = tid >> 6, lane = tid & 63;
    int quad = lane >> 4, l16 = lane & 15;
    int wr = wid >> 1, wc = wid & 1;
    int m0 = blockIdx.x * 64;
    int chunk = tid & 15, rip = tid >> 4;

    f32x4 acc[2][4];
#pragma unroll
    for (int st = 0; st < 2; ++st)
#pragma unroll
        for (int nt = 0; nt < 4; ++nt) acc[st][nt] = (f32x4){0.f, 0.f, 0.f, 0.f};

    // ---- prologue: stage B(seg 0), zero A_acc, load edge ranges ----
#pragma unroll
    for (int p = 0; p < 8; ++p) {
        int rr = p * 16 + rip;
        uint4 v = *((const uint4*)(Wt + rr * 128) + chunk);
        *(uint4*)(&B_lds[rr * LDB + chunk * 8]) = v;
    }
#pragma unroll
    for (int i = 0; i < 8; ++i) {
        int idx = tid + 256 * i;
        int rz = idx >> 5, c4 = idx & 31;
        *(float4*)(&A_acc[rz * LDAA + c4 * 4]) = (float4){0.f, 0.f, 0.f, 0.f};
    }
    if (tid < 16) {
        int r = tid >> 1;
        int nd = (tid & 1) ? ((m0 + 64 < NN) ? m0 + 64 : NN) : m0;
        erange[tid] = starts[(size_t)r * NN + nd];
    }
    __syncthreads();   // S0: B0 + zeros + erange ready

    // ---- segment 0 (root): A frags direct from xs (split format) ----
#pragma unroll
    for (int kt = 0; kt < 4; ++kt) {
        int ko = kt * 32 + quad * 8;
        bf16x8 b[4];
#pragma unroll
        for (int nt = 0; nt < 4; ++nt)
            b[nt] = *(const bf16x8*)(&B_lds[(wc * 64 + nt * 16 + l16) * LDB + ko]);
#pragma unroll
        for (int st = 0; st < 2; ++st) {
            int row = wr * 32 + st * 16 + l16;
            int node = m0 + row;
            node = node < NN ? node : NN - 1;
            int off = (kt < 2) ? ko : (ko - 64);
            const unsigned* xp = xs + (size_t)node * 64 + off;
            uint4 u0 = *(const uint4*)xp;
            uint4 u1 = *(const uint4*)(xp + 4);
            union { unsigned short u[8]; bf16x8 v; } au;
            unsigned w[8] = {u0.x, u0.y, u0.z, u0.w, u1.x, u1.y, u1.z, u1.w};
#pragma unroll
            for (int j = 0; j < 8; ++j)
                au.u[j] = (kt < 2) ? (unsigned short)(w[j] & 0xffffu)
                                   : (unsigned short)(w[j] >> 16);
#pragma unroll
            for (int nt = 0; nt < 4; ++nt)
                acc[st][nt] = __builtin_amdgcn_mfma_f32_16x16x32_bf16(
                    au.v, b[nt], acc[st][nt], 0, 0, 0);
        }
    }
    __syncthreads();   // S1: B_lds free for restaging

    // ---- relations ----
    for (int r = 0; r < 8; ++r) {
        // stage B(seg r+1) — overlaps with gather
        const unsigned short* Bbase = Wt + (r + 1) * 16384;
#pragma unroll
        for (int p = 0; p < 8; ++p) {
            int rr = p * 16 + rip;
            uint4 v = *((const uint4*)(Bbase + rr * 128) + chunk);
            *(uint4*)(&B_lds[rr * LDB + chunk * 8]) = v;
        }
        // per-row inverse degree
        if (tid < 64) {
            int node = m0 + tid;
            float iv = 0.f;
            if (node < NN) {
                size_t k = (size_t)r * NN + node;
                unsigned d = starts[k + 1] - starts[k];
                iv = (d > 1u) ? (1.f / (float)d) : 1.f;
            }
            invdeg[tid] = iv;
        }
        // gather: wave-per-edge, edges for this (block, relation) are contiguous
        unsigned e_lo = erange[2 * r], e_hi = erange[2 * r + 1];
        unsigned base = e_lo + (unsigned)wid * 2u;
        unsigned eA = base + 8u * (unsigned)lane;
        unsigned pkA = (eA < e_hi) ? epk[eA] : 0u;
        unsigned pkB = (eA + 1u < e_hi) ? epk[eA + 1u] : 0u;
        int nj = (e_hi > base) ? (int)((e_hi - base + 7u) >> 3) : 0;
        for (int j = 0; j < nj; j += 2) {
            unsigned e0 = base + 8u * (unsigned)j;
            unsigned pk0, pk1, pk2, pk3;
            if (j < 63) {
                pk0 = __shfl(pkA, j);
                pk1 = __shfl(pkB, j);
                pk2 = __shfl(pkA, j + 1);
                pk3 = __shfl(pkB, j + 1);
            } else {   // cold fallback (>512 edges in range)
                pk0 = (e0 < e_hi) ? epk[e0] : 0u;
                pk1 = (e0 + 1u < e_hi) ? epk[e0 + 1u] : 0u;
                pk2 = (e0 + 8u < e_hi) ? epk[e0 + 8u] : 0u;
                pk3 = (e0 + 9u < e_hi) ? epk[e0 + 9u] : 0u;
            }
            bool v0 = e0 < e_hi, v1 = e0 + 1u < e_hi, v2 = e0 + 8u < e_hi, v3 = e0 + 9u < e_hi;
            unsigned q0 = xs[(size_t)(pk0 & 0x1ffffu) * 64 + lane];
            unsigned q1 = xs[(size_t)(pk1 & 0x1ffffu) * 64 + lane];
            unsigned q2 = xs[(size_t)(pk2 & 0x1ffffu) * 64 + lane];
            unsigned q3 = xs[(size_t)(pk3 & 0x1ffffu) * 64 + lane];
            if (v0) {
                float* ap = &A_acc[(pk0 >> 17) * LDAA + lane];
                atomicAdd(ap, __uint_as_float(q0 << 16));
                atomicAdd(ap + 64, __uint_as_float(q0 & 0xffff0000u));
            }
            if (v1) {
                float* ap = &A_acc[(pk1 >> 17) * LDAA + lane];
                atomicAdd(ap, __uint_as_float(q1 << 16));
                atomicAdd(ap + 64, __uint_as_float(q1 & 0xffff0000u));
            }
            if (v2) {
                float* ap = &A_acc[(pk2 >> 17) * LDAA + lane];
                atomicAdd(ap, __uint_as_float(q2 << 16));
                atomicAdd(ap + 64, __uint_as_float(q2 & 0xffff0000u));
            }
            if (v3) {
                float* ap = &A_acc[(pk3 >> 17) * LDAA + lane];
                atomicAdd(ap, __uint_as_float(q3 << 16));
                atomicAdd(ap + 64, __uint_as_float(q3 & 0xffff0000u));
            }
        }
        __syncthreads();   // S2: A_acc + B + invdeg ready

        // MFMA over segment r+1
#pragma unroll
        for (int kt = 0; kt < 4; ++kt) {
            int ko = kt * 32 + quad * 8;
            bf16x8 b[4];
#pragma unroll
            for (int nt = 0; nt < 4; ++nt)
                b[nt] = *(const bf16x8*)(&B_lds[(wc * 64 + nt * 16 + l16) * LDB + ko]);
#pragma unroll
            for (int st = 0; st < 2; ++st) {
                int row = wr * 32 + st * 16 + l16;
                const float* ap = &A_acc[row * LDAA + ko];
                float4 f0 = *(const float4*)ap;
                float4 f1 = *(const float4*)(ap + 4);
                float sc = invdeg[row];
                union { ushort2 p[4]; bf16x8 v; } au;
                au.p[0] = cvt2bf(f0.x * sc, f0.y * sc);
                au.p[1] = cvt2bf(f0.z * sc, f0.w * sc);
                au.p[2] = cvt2bf(f1.x * sc, f1.y * sc);
                au.p[3] = cvt2bf(f1.z * sc, f1.w * sc);
#pragma unroll
                for (int nt = 0; nt < 4; ++nt)
                    acc[st][nt] = __builtin_amdgcn_mfma_f32_16x16x32_bf16(
                        au.v, b[nt], acc[st][nt], 0, 0, 0);
            }
        }
        __syncthreads();   // S3: A_acc/B reads done

        if (r < 7) {       // re-zero A_acc for next relation
#pragma unroll
            for (int i = 0; i < 8; ++i) {
                int idx = tid + 256 * i;
                int rz = idx >> 5, c4 = idx & 31;
                *(float4*)(&A_acc[rz * LDAA + c4 * 4]) = (float4){0.f, 0.f, 0.f, 0.f};
            }
            __syncthreads();   // S4: zeros visible before next gather
        }
    }

    // ---- epilogue: bias + relu ----
    if (outF) {
#pragma unroll
        for (int st = 0; st < 2; ++st) {
            int rowbase = m0 + wr * 32 + st * 16 + quad * 4;
#pragma unroll
            for (int nt = 0; nt < 4; ++nt) {
                int n = wc * 64 + nt * 16 + l16;
                float bv = bias[n];
#pragma unroll
                for (int rg = 0; rg < 4; ++rg) {
                    int node = rowbase + rg;
                    if (node < NN) {
                        float v = acc[st][nt][rg] + bv;
                        outF[(size_t)node * HH + n] = v > 0.f ? v : 0.f;
                    }
                }
            }
        }
    } else {
        // route through A_acc to emit split-format bf16 with coalesced stores
#pragma unroll
        for (int st = 0; st < 2; ++st) {
            int rowb = wr * 32 + st * 16 + quad * 4;
#pragma unroll
            for (int nt = 0; nt < 4; ++nt) {
                int n = wc * 64 + nt * 16 + l16;
                float bv = bias[n];
#pragma unroll
                for (int rg = 0; rg < 4; ++rg) {
                    float v = acc[st][nt][rg] + bv;
                    A_acc[(rowb + rg) * LDAA + n] = v > 0.f ? v : 0.f;
                }
            }
        }
        __syncthreads();
#pragma unroll
        for (int i = 0; i < 16; ++i) {
            int idx = tid + 256 * i;
            int row = idx >> 6, c = idx & 63;
            int node = m0 + row;
            if (node < NN) {
                float lo = A_acc[row * LDAA + c];
                float hi = A_acc[row * LDAA + 64 + c];
                outS[(size_t)node * 64 + c] =
                    (unsigned)f2bf(lo) | ((unsigned)f2bf(hi) << 16);
            }
        }
    }
}

extern "C" void kernel_launch(void* const* d_in, const int* in_sizes, int n_in,
                              void* d_out, int out_size, void* d_ws, size_t ws_size,
                              hipStream_t stream) {
    const int* node_idx = (const int*)d_in[0];
    const int* eidx     = (const int*)d_in[1];
    const int* etype    = (const int*)d_in[2];
    const float* emb    = (const float*)d_in[3];
    const float* Wr0    = (const float*)d_in[4];
    const float* Wq0    = (const float*)d_in[5];
    const float* b0     = (const float*)d_in[6];
    const float* Wr1    = (const float*)d_in[7];
    const float* Wq1    = (const float*)d_in[8];
    const float* b1     = (const float*)d_in[9];
    const int* esrc = eidx;
    const int* edst = eidx + NE;

    char* ws = (char*)d_ws;
    size_t off = 0;
    auto alloc = [&](size_t bytes) -> void* {
        void* p = ws + off;
        off = (off + bytes + 255) & ~(size_t)255;
        return p;
    };
    unsigned* counts   = (unsigned*)alloc((size_t)NK * 4);
    unsigned* starts   = (unsigned*)alloc((size_t)(NK + 1) * 4);
    unsigned* cursor   = (unsigned*)alloc((size_t)NK * 4);
    unsigned* bsums    = (unsigned*)alloc(1024 * 4);
    unsigned* epk      = (unsigned*)alloc((size_t)NE * 4);
    unsigned* xs       = (unsigned*)alloc((size_t)NN * 64 * 4);
    unsigned* y0s      = (unsigned*)alloc((size_t)NN * 64 * 4);
    unsigned short* Wt = (unsigned short*)alloc((size_t)2 * 9 * 16384 * 2);
    (void)ws_size; (void)n_in; (void)in_sizes; (void)out_size;

    hipMemsetAsync(counts, 0, (size_t)NK * 4, stream);
    convertW<<<(2 * 9 * 16384 + 255) / 256, 256, 0, stream>>>(Wr0, Wq0, Wr1, Wq1, Wt);
    convertX<<<(NN * 64 + 255) / 256, 256, 0, stream>>>(node_idx, emb, xs);
    countDeg<<<(NE + 255) / 256, 256, 0, stream>>>(edst, etype, counts);
    scan1<<<SCAN_BLOCKS, 256, 0, stream>>>(counts, starts, bsums);
    scan2<<<1, 1024, 0, stream>>>(bsums, SCAN_BLOCKS);
    scan3<<<(NK + 255) / 256, 256, 0, stream>>>(starts, cursor, bsums);
    scatterEdges<<<(NE + 255) / 256, 256, 0, stream>>>(esrc, edst, etype, cursor, epk);

    int nblk = (NN + 63) / 64;
    rgcnFused<<<nblk, 256, 0, stream>>>(xs, starts, epk, Wt, b0, nullptr, y0s);
    rgcnFused<<<nblk, 256, 0, stream>>>(y0s, starts, epk, Wt + 147456, b1,
                                        (float*)d_out, nullptr);
}

// Round 5
// 694.148 us; speedup vs baseline: 4.1093x; 4.1093x over previous
//
#include <hip/hip_runtime.h>
#include <hip/hip_bf16.h>

typedef short bf16x8 __attribute__((ext_vector_type(8)));
typedef float f32x4 __attribute__((ext_vector_type(4)));

constexpr int NN = 100000;           // nodes
constexpr int NE = 1600000;          // edges
constexpr int HH = 128;              // hidden
constexpr int NR = 8;                // relations
constexpr int NK = NR * NN;          // 800000 keys, key = dst*8 + rel
constexpr int SCAN_BLOCKS = (NK + 1023) / 1024;   // 782

__device__ __forceinline__ unsigned short f2bf(float f) {
    unsigned b = __float_as_uint(f);
    b += 0x7fffu + ((b >> 16) & 1u);       // round-to-nearest-even
    return (unsigned short)(b >> 16);
}

// ---- W convert + transpose: Wt[L][s][f][d] (bf16) from fp32 W[d][f] ----
__global__ void convertW(const float* __restrict__ Wr0, const float* __restrict__ Wq0,
                         const float* __restrict__ Wr1, const float* __restrict__ Wq1,
                         unsigned short* __restrict__ Wt) {
    int o = blockIdx.x * blockDim.x + threadIdx.x;
    if (o >= 2 * 9 * 128 * 128) return;
    int L = o / 147456;
    int rem = o - L * 147456;
    int s = rem >> 14;
    int p = rem & 16383;
    int f = p >> 7;
    int d = p & 127;
    const float* Wq = L ? Wq1 : Wq0;
    const float* Wr = L ? Wr1 : Wr0;
    float v = (s == 0) ? Wq[d * 128 + f] : Wr[((s - 1) * 128 + d) * 128 + f];
    Wt[o] = f2bf(v);
}

// ---- x -> bf16 pairs: xb32[n][l] = pack(x[n][2l], x[n][2l+1]) ----
__global__ void convertX(const int* __restrict__ node_idx, const float* __restrict__ emb,
                         unsigned* __restrict__ xb32) {
    int i = blockIdx.x * blockDim.x + threadIdx.x;
    if (i >= NN * 64) return;
    int n = i >> 6, dp = i & 63;
    int row = node_idx[n];
    float2 v = *((const float2*)(emb + (size_t)row * HH) + dp);
    xb32[(size_t)n * 64 + dp] = (unsigned)f2bf(v.x) | ((unsigned)f2bf(v.y) << 16);
}

// ---- degree count per (dst,rel) key ----
__global__ void countDeg(const int* __restrict__ edst, const int* __restrict__ etype,
                         unsigned* __restrict__ counts) {
    int e = blockIdx.x * blockDim.x + threadIdx.x;
    if (e >= NE) return;
    int key = edst[e] * NR + etype[e];
    atomicAdd(&counts[key], 1u);
}

// ---- 2-level exclusive scan of counts[NK] -> starts ----
__global__ void scan1(const unsigned* __restrict__ counts, unsigned* __restrict__ starts,
                      unsigned* __restrict__ bsums) {
    __shared__ unsigned sh[256];
    int tid = threadIdx.x;
    int base = blockIdx.x * 1024 + tid * 4;
    unsigned c[4], tsum = 0;
#pragma unroll
    for (int j = 0; j < 4; ++j) {
        c[j] = (base + j < NK) ? counts[base + j] : 0u;
        tsum += c[j];
    }
    sh[tid] = tsum;
    __syncthreads();
    for (int ofs = 1; ofs < 256; ofs <<= 1) {
        unsigned v = (tid >= ofs) ? sh[tid - ofs] : 0u;
        __syncthreads();
        sh[tid] += v;
        __syncthreads();
    }
    unsigned run = sh[tid] - tsum;
#pragma unroll
    for (int j = 0; j < 4; ++j) {
        if (base + j < NK) starts[base + j] = run;
        run += c[j];
    }
    if (tid == 255) bsums[blockIdx.x] = sh[255];
}

__global__ void scan2(unsigned* __restrict__ bsums, int nb) {
    __shared__ unsigned sh[1024];
    int tid = threadIdx.x;
    unsigned v = (tid < nb) ? bsums[tid] : 0u;
    sh[tid] = v;
    __syncthreads();
    for (int ofs = 1; ofs < 1024; ofs <<= 1) {
        unsigned t = (tid >= ofs) ? sh[tid - ofs] : 0u;
        __syncthreads();
        sh[tid] += t;
        __syncthreads();
    }
    if (tid < nb) bsums[tid] = sh[tid] - v;
}

__global__ void scan3(unsigned* __restrict__ starts, unsigned* __restrict__ cursor,
                      const unsigned* __restrict__ bsums) {
    int i = blockIdx.x * blockDim.x + threadIdx.x;
    if (i >= NK) return;
    unsigned v = starts[i] + bsums[i >> 10];
    starts[i] = v;
    cursor[i] = v;
    if (i == 0) starts[NK] = NE;
}

// ---- counting-sort scatter: epk holds src node per edge, sorted by (dst,rel) ----
__global__ void scatterEdges(const int* __restrict__ esrc, const int* __restrict__ edst,
                             const int* __restrict__ etype, unsigned* __restrict__ cursor,
                             unsigned* __restrict__ epk) {
    int e = blockIdx.x * blockDim.x + threadIdx.x;
    if (e >= NE) return;
    int key = edst[e] * NR + etype[e];
    unsigned pos = atomicAdd(&cursor[key], 1u);
    epk[pos] = (unsigned)esrc[e];
}

// ---- gather+mean: ONE WAVE PER DST NODE, all 8 relations, 8-deep load ILP ----
// xb32: [NN][64] bf16-pair dwords.  h32: [NN][8][64] node-major output.
__global__ __launch_bounds__(256) void gatherNode(
        const unsigned* __restrict__ starts, const unsigned* __restrict__ epk,
        const unsigned* __restrict__ xb32, unsigned* __restrict__ h32) {
    int node = blockIdx.x * 4 + (threadIdx.x >> 6);
    if (node >= NN) return;
    int lane = threadIdx.x & 63;

    // 9 CSR boundaries for this node's 8 relation buckets
    unsigned bv = 0;
    if (lane < 9) bv = starts[(size_t)node * 8 + lane];
    unsigned b[9];
#pragma unroll
    for (int r = 0; r < 9; ++r) b[r] = __shfl(bv, r);
    unsigned s0 = b[0], s1 = b[8];
    int cnt = (int)__builtin_amdgcn_readfirstlane((int)(s1 - s0));

    float a[8][2];
#pragma unroll
    for (int r = 0; r < 8; ++r) { a[r][0] = 0.f; a[r][1] = 0.f; }

    for (int c0 = 0; c0 < cnt; c0 += 64) {
        unsigned myE = s0 + (unsigned)c0 + (unsigned)lane;
        unsigned pk = (myE < s1) ? epk[myE] : 0u;
        // per-lane relation id of its edge (edges are rel-sorted in segment)
        unsigned rl = 0;
#pragma unroll
        for (int r = 1; r < 8; ++r) rl += (myE >= b[r]) ? 1u : 0u;
        pk |= rl << 24;
        int cend = cnt - c0;
        if (cend > 64) cend = 64;
        for (int base = 0; base < cend; base += 8) {
            int m = cend - base;
            if (m > 8) m = 8;
            unsigned pj[8], qj[8];
#pragma unroll
            for (int j = 0; j < 8; ++j)
                pj[j] = (j < m) ? (unsigned)__shfl((int)pk, base + j) : 0u;
#pragma unroll
            for (int j = 0; j < 8; ++j)
                if (j < m) qj[j] = xb32[(size_t)(pj[j] & 0x1ffffu) * 64 + lane];
#pragma unroll
            for (int j = 0; j < 8; ++j) {
                if (j < m) {
                    float lo = __uint_as_float(qj[j] << 16);
                    float hi = __uint_as_float(qj[j] & 0xffff0000u);
                    switch (__builtin_amdgcn_readfirstlane((int)(pj[j] >> 24))) {
                        case 0: a[0][0] += lo; a[0][1] += hi; break;
                        case 1: a[1][0] += lo; a[1][1] += hi; break;
                        case 2: a[2][0] += lo; a[2][1] += hi; break;
                        case 3: a[3][0] += lo; a[3][1] += hi; break;
                        case 4: a[4][0] += lo; a[4][1] += hi; break;
                        case 5: a[5][0] += lo; a[5][1] += hi; break;
                        case 6: a[6][0] += lo; a[6][1] += hi; break;
                        default: a[7][0] += lo; a[7][1] += hi; break;
                    }
                }
            }
        }
    }

    // mean-normalize and store 8 contiguous rows (2 KB per node)
#pragma unroll
    for (int r = 0; r < 8; ++r) {
        unsigned c = b[r + 1] - b[r];
        float inv = (c > 1u) ? (1.f / (float)c) : 1.f;
        unsigned out = (unsigned)f2bf(a[r][0] * inv) |
                       ((unsigned)f2bf(a[r][1] * inv) << 16);
        h32[((size_t)node * 8 + r) * 64 + lane] = out;
    }
}

// ---- fused layer GEMM: out[M,128] = relu([x|h0..h7] @ Wt^T + b) ----
// Tile: 64 nodes x 128 feats per block; 4 waves as 2x2; 16x16x32 bf16 MFMA.
// NOTE: x and outB may alias (layer 0 writes in place: each block reads x only
// for its own 64 rows at s=0, before its epilogue writes them) -> no restrict.
__global__ __launch_bounds__(256) void rgcnGemm(const unsigned short* x,
                                                const unsigned short* __restrict__ h,
                                                const unsigned short* __restrict__ Wt,
                                                const float* __restrict__ bias,
                                                float* __restrict__ outF,
                                                unsigned short* outB) {
    constexpr int LDA = 136;   // +8 bf16 pad
    __shared__ __align__(16) unsigned short A_lds[64 * LDA];
    __shared__ __align__(16) unsigned short B_lds[128 * LDA];

    int tid = threadIdx.x;
    int wid = tid >> 6, lane = tid & 63;
    int quad = lane >> 4, l16 = lane & 15;
    int wr = wid >> 1, wc = wid & 1;
    int m0 = blockIdx.x * 64;
    int chunk = tid & 15, rip = tid >> 4;

    f32x4 acc[2][4];
#pragma unroll
    for (int st = 0; st < 2; ++st)
#pragma unroll
        for (int nt = 0; nt < 4; ++nt) acc[st][nt] = (f32x4){0.f, 0.f, 0.f, 0.f};

    for (int s = 0; s < 9; ++s) {
        __syncthreads();
#pragma unroll
        for (int p = 0; p < 4; ++p) {
            int r = p * 16 + rip;
            int node = m0 + r;
            node = node < NN ? node : NN - 1;
            const unsigned short* rp = (s == 0)
                ? (x + (size_t)node * HH)
                : (h + ((size_t)node * 8 + (s - 1)) * HH);
            uint4 v = *((const uint4*)rp + chunk);
            *(uint4*)(&A_lds[r * LDA + chunk * 8]) = v;
        }
        const unsigned short* Bbase = Wt + s * 16384;
#pragma unroll
        for (int p = 0; p < 8; ++p) {
            int r = p * 16 + rip;
            uint4 v = *((const uint4*)(Bbase + r * 128) + chunk);
            *(uint4*)(&B_lds[r * LDA + chunk * 8]) = v;
        }
        __syncthreads();
#pragma unroll
        for (int kt = 0; kt < 4; ++kt) {
            int ko = kt * 32 + quad * 8;
            bf16x8 a[2], b[4];
            a[0] = *(const bf16x8*)(&A_lds[(wr * 32 + l16) * LDA + ko]);
            a[1] = *(const bf16x8*)(&A_lds[(wr * 32 + 16 + l16) * LDA + ko]);
#pragma unroll
            for (int nt = 0; nt < 4; ++nt)
                b[nt] = *(const bf16x8*)(&B_lds[(wc * 64 + nt * 16 + l16) * LDA + ko]);
#pragma unroll
            for (int st = 0; st < 2; ++st)
#pragma unroll
                for (int nt = 0; nt < 4; ++nt)
                    acc[st][nt] = __builtin_amdgcn_mfma_f32_16x16x32_bf16(
                        a[st], b[nt], acc[st][nt], 0, 0, 0);
        }
    }
    // epilogue: C/D layout col=lane&15, row=quad*4+reg
#pragma unroll
    for (int st = 0; st < 2; ++st) {
        int rowbase = m0 + wr * 32 + st * 16 + quad * 4;
#pragma unroll
        for (int nt = 0; nt < 4; ++nt) {
            int n = wc * 64 + nt * 16 + l16;
            float bv = bias[n];
#pragma unroll
            for (int rg = 0; rg < 4; ++rg) {
                int node = rowbase + rg;
                if (node < NN) {
                    float v = acc[st][nt][rg] + bv;
                    v = v > 0.f ? v : 0.f;
                    if (outF) outF[(size_t)node * HH + n] = v;
                    else outB[(size_t)node * HH + n] = f2bf(v);
                }
            }
        }
    }
}

extern "C" void kernel_launch(void* const* d_in, const int* in_sizes, int n_in,
                              void* d_out, int out_size, void* d_ws, size_t ws_size,
                              hipStream_t stream) {
    const int* node_idx = (const int*)d_in[0];
    const int* eidx     = (const int*)d_in[1];
    const int* etype    = (const int*)d_in[2];
    const float* emb    = (const float*)d_in[3];
    const float* Wr0    = (const float*)d_in[4];
    const float* Wq0    = (const float*)d_in[5];
    const float* b0     = (const float*)d_in[6];
    const float* Wr1    = (const float*)d_in[7];
    const float* Wq1    = (const float*)d_in[8];
    const float* b1     = (const float*)d_in[9];
    const int* esrc = eidx;
    const int* edst = eidx + NE;

    char* ws = (char*)d_ws;
    size_t off = 0;
    auto alloc = [&](size_t bytes) -> void* {
        void* p = ws + off;
        off = (off + bytes + 255) & ~(size_t)255;
        return p;
    };
    // Workspace budget: ~243.8 MB total (under round-1's proven-good 247 MB).
    unsigned* counts   = (unsigned*)alloc((size_t)NK * 4);        // also reused as cursor
    unsigned* starts   = (unsigned*)alloc((size_t)(NK + 1) * 4);
    unsigned* bsums    = (unsigned*)alloc(1024 * 4);
    unsigned* epk      = (unsigned*)alloc((size_t)NE * 4);
    unsigned* xb32     = (unsigned*)alloc((size_t)NN * 64 * 4);
    unsigned* h32      = (unsigned*)alloc((size_t)NN * 8 * 64 * 4);
    unsigned short* Wt = (unsigned short*)alloc((size_t)2 * 9 * 16384 * 2);
    unsigned* cursor = counts;   // counts is dead after scan1; overlay
    (void)ws_size; (void)n_in; (void)in_sizes; (void)out_size;

    hipMemsetAsync(counts, 0, (size_t)NK * 4, stream);
    convertW<<<(2 * 9 * 16384 + 255) / 256, 256, 0, stream>>>(Wr0, Wq0, Wr1, Wq1, Wt);
    convertX<<<(NN * 64 + 255) / 256, 256, 0, stream>>>(node_idx, emb, xb32);
    countDeg<<<(NE + 255) / 256, 256, 0, stream>>>(edst, etype, counts);
    scan1<<<SCAN_BLOCKS, 256, 0, stream>>>(counts, starts, bsums);
    scan2<<<1, 1024, 0, stream>>>(bsums, SCAN_BLOCKS);
    scan3<<<(NK + 255) / 256, 256, 0, stream>>>(starts, cursor, bsums);
    scatterEdges<<<(NE + 255) / 256, 256, 0, stream>>>(esrc, edst, etype, cursor, epk);

    int nblk = (NN + 63) / 64;
    // layer 0: gather on x, GEMM -> relu -> bf16 pairs written in place into xb32
    gatherNode<<<(NN + 3) / 4, 256, 0, stream>>>(starts, epk, xb32, h32);
    rgcnGemm<<<nblk, 256, 0, stream>>>((const unsigned short*)xb32,
                                       (const unsigned short*)h32, Wt, b0,
                                       nullptr, (unsigned short*)xb32);
    // layer 1: gather on relu(out0), GEMM -> relu -> fp32 d_out
    gatherNode<<<(NN + 3) / 4, 256, 0, stream>>>(starts, epk, xb32, h32);
    rgcnGemm<<<nblk, 256, 0, stream>>>((const unsigned short*)xb32,
                                       (const unsigned short*)h32, Wt + 147456, b1,
                                       (float*)d_out, nullptr);
}